// Round 2
// baseline (15909.856 us; speedup 1.0000x reference)
//
#include <hip/hip_runtime.h>
#include <cstdint>
#include <cstddef>

// LSTM autoregressive decoder, BATCH=32, T=256, VOCAB=8192, HIDDEN=1024.
// Per step: kA (h@[Wp|Wh] partials, scalar-load h + pure-FMA) ->
//           kB (logits + gumbel argmax + preds + LSTM cell, one block per b).
// jax threefry (partitionable variant) reproduced bit-exactly.

namespace {

constexpr int BB = 32;       // batch
constexpr int TT = 256;      // time steps
constexpr int VV = 8192;     // vocab
constexpr int HH = 1024;     // hidden
constexpr int ZC = 4096;     // 4*H
constexpr int NCOL = VV + ZC;   // 12288 columns (logits | z)
constexpr int SPL = 4;       // u-split for kA (1024/256)
constexpr int K0S = 8;       // u-split for K0 (9216/1152)

__host__ __device__ inline uint32_t rotl(uint32_t v, int r) {
  return (v << r) | (v >> (32 - r));
}

// Exact jax threefry2x32 (20 rounds).
__host__ __device__ inline void tf2x32(uint32_t k0, uint32_t k1,
                                       uint32_t x0, uint32_t x1,
                                       uint32_t &o0, uint32_t &o1) {
  const uint32_t ks2 = k0 ^ k1 ^ 0x1BD11BDAu;
  x0 += k0; x1 += k1;
#define R4A { x0+=x1; x1=rotl(x1,13); x1^=x0; x0+=x1; x1=rotl(x1,15); x1^=x0; \
              x0+=x1; x1=rotl(x1,26); x1^=x0; x0+=x1; x1=rotl(x1, 6); x1^=x0; }
#define R4B { x0+=x1; x1=rotl(x1,17); x1^=x0; x0+=x1; x1=rotl(x1,29); x1^=x0; \
              x0+=x1; x1=rotl(x1,16); x1^=x0; x0+=x1; x1=rotl(x1,24); x1^=x0; }
  R4A; x0 += k1;  x1 += ks2 + 1u;
  R4B; x0 += ks2; x1 += k0 + 2u;
  R4A; x0 += k0;  x1 += k1 + 3u;
  R4B; x0 += k1;  x1 += ks2 + 4u;
  R4A; x0 += ks2; x1 += k0 + 5u;
#undef R4A
#undef R4B
  o0 = x0; o1 = x1;
}

__device__ inline float sigf(float x) { return 1.0f / (1.0f + expf(-x)); }

// ---------------------------------------------------------------------------
// K0: z0 partials = x0 @ Wi + h0 @ Wh  (K = VOCAB + HIDDEN = 9216, split x8)
__global__ __launch_bounds__(256) void k0_partial(
    const float* __restrict__ inputs,   // [B][T][V], use t=0
    const float* __restrict__ h0,       // [B][H]
    const float* __restrict__ Wi,       // [V][ZC]
    const float* __restrict__ Wh,       // [H][ZC]
    float* __restrict__ zpart0)         // [K0S][B][ZC]
{
  const int cb = blockIdx.x % (ZC / 64);
  const int s  = blockIdx.x / (ZC / 64);
  const int c  = threadIdx.x & 63;
  const int w  = threadIdx.x >> 6;
  const int col = cb * 64 + c;
  const int u0 = s * 1152 + w * 288;

  float acc[BB];
#pragma unroll
  for (int b = 0; b < BB; ++b) acc[b] = 0.0f;

  for (int ui = 0; ui < 288; ++ui) {
    const int u = u0 + ui;
    const float wv = (u < VV) ? Wi[(size_t)u * ZC + col]
                              : Wh[(size_t)(u - VV) * ZC + col];
#pragma unroll
    for (int b = 0; b < BB; ++b) {
      const float a = (u < VV) ? inputs[(size_t)b * TT * VV + u]
                               : h0[b * HH + (u - VV)];
      acc[b] = fmaf(a, wv, acc[b]);
    }
  }

  __shared__ float red[4][BB][64];   // 32 KiB
#pragma unroll
  for (int b = 0; b < BB; ++b) red[w][b][c] = acc[b];
  __syncthreads();
  for (int i = threadIdx.x; i < BB * 64; i += 256) {
    const int b = i >> 6, cc = i & 63;
    const float s4 = red[0][b][cc] + red[1][b][cc] + red[2][b][cc] + red[3][b][cc];
    zpart0[((size_t)s * BB + b) * ZC + cb * 64 + cc] = s4;
  }
}

// K0b: zfull0[b][j] = bh[j] + sum_s zpart0[s][b][j]
__global__ __launch_bounds__(256) void k0_reduce(
    const float* __restrict__ zpart0, const float* __restrict__ bh,
    float* __restrict__ zfull0)
{
  const int idx = blockIdx.x * 256 + threadIdx.x;  // B*ZC = 131072
  const int b = idx / ZC, j = idx % ZC;
  float s = bh[j];
#pragma unroll
  for (int k = 0; k < K0S; ++k) s += zpart0[((size_t)k * BB + b) * ZC + j];
  zfull0[idx] = s;
}

// kInit: cell for step 0 from zfull0 -> cbuf, hbuf. grid 128 x 256.
__global__ __launch_bounds__(256) void kInit(
    const float* __restrict__ zfull0, const float* __restrict__ c0,
    float* __restrict__ cbuf, float* __restrict__ hbuf)
{
  const int idx = blockIdx.x * 256 + threadIdx.x;   // B*H = 32768
  const int b = idx >> 10, u = idx & 1023;
  const float* z = zfull0 + (size_t)b * ZC;
  const float zi = z[u], zf = z[HH + u], zg = z[2 * HH + u], zo = z[3 * HH + u];
  const float cc = sigf(zf) * c0[idx] + sigf(zi) * tanhf(zg);
  cbuf[idx] = cc;
  hbuf[idx] = sigf(zo) * tanhf(cc);
}

// ---------------------------------------------------------------------------
// kA: part[s][b][col] partials for [h@Wp | h@Wh]. grid 192*SPL=768, 256 thr.
// h addresses are wave-uniform (w via readfirstlane) -> scalar s_load path,
// leaving the VALU as pure v_fmac_f32 (SGPR src0).
__global__ __launch_bounds__(256) void kA(
    const float* __restrict__ hbuf,     // [B][H]
    const float* __restrict__ Wp,       // [H][V]
    const float* __restrict__ Wh,       // [H][ZC]
    float* __restrict__ part)           // [SPL][B][NCOL]
{
  const int cb = blockIdx.x % (NCOL / 64);
  const int s  = blockIdx.x / (NCOL / 64);
  const int c  = threadIdx.x & 63;
  const int w  = __builtin_amdgcn_readfirstlane(threadIdx.x >> 6);
  const int col = cb * 64 + c;

  const float* W; int ldw, wcol;
  if (col < VV) { W = Wp; ldw = VV; wcol = col; }
  else          { W = Wh; ldw = ZC; wcol = col - VV; }

  const float* hb = hbuf + s * 256 + w * 64;       // + b*HH per b (uniform)
  const float* wp = W + (size_t)(s * 256 + w * 64) * ldw + wcol;

  float acc[BB];
#pragma unroll
  for (int b = 0; b < BB; ++b) acc[b] = 0.0f;

  for (int uc = 0; uc < 8; ++uc) {
    float wv[8];
#pragma unroll
    for (int k = 0; k < 8; ++k) wv[k] = wp[(size_t)(uc * 8 + k) * ldw];
#pragma unroll
    for (int b = 0; b < BB; ++b) {
      const float* hp = hb + b * HH + uc * 8;      // fully uniform address
      acc[b] = fmaf(hp[0], wv[0], acc[b]);
      acc[b] = fmaf(hp[1], wv[1], acc[b]);
      acc[b] = fmaf(hp[2], wv[2], acc[b]);
      acc[b] = fmaf(hp[3], wv[3], acc[b]);
      acc[b] = fmaf(hp[4], wv[4], acc[b]);
      acc[b] = fmaf(hp[5], wv[5], acc[b]);
      acc[b] = fmaf(hp[6], wv[6], acc[b]);
      acc[b] = fmaf(hp[7], wv[7], acc[b]);
    }
  }

  __shared__ float red[4][BB][64];   // 32 KiB
#pragma unroll
  for (int b = 0; b < BB; ++b) red[w][b][c] = acc[b];
  __syncthreads();
  for (int i = threadIdx.x; i < BB * 64; i += 256) {
    const int b = i >> 6, cc = i & 63;
    const float s4 = red[0][b][cc] + red[1][b][cc] + red[2][b][cc] + red[3][b][cc];
    part[((size_t)s * BB + b) * NCOL + cb * 64 + cc] = s4;
  }
}

// ---------------------------------------------------------------------------
// kB: per-b block (grid=32, 1024 thr): logits = sum_s part + bp -> out;
// gumbel via threefry; in-block argmax (first-index ties); preds zero+onehot;
// then LSTM cell for the next step (u = tid).
__global__ __launch_bounds__(1024) void kB(
    const float* __restrict__ part,     // [SPL][B][NCOL]
    const float* __restrict__ bp,       // [V]
    const float* __restrict__ bh,       // [ZC]
    const float* __restrict__ Wi,       // [V][ZC]
    float* __restrict__ logits_out,     // [B][T][V]
    float* __restrict__ preds_out,      // [B][T][V]
    float* __restrict__ cbuf, float* __restrict__ hbuf,   // [B][H]
    uint32_t ck0, uint32_t ck1, int t, int do_cell)
{
  const int b = blockIdx.x;
  const int tid = threadIdx.x;
  float* lg_row = logits_out + ((size_t)b * TT + t) * VV;
  float* pr_row = preds_out  + ((size_t)b * TT + t) * VV;

  float best = -3.4e38f; int besti = 0x7fffffff;
  for (int it = 0; it < VV / 1024; ++it) {
    const int v = it * 1024 + tid;
    float lg = bp[v];
#pragma unroll
    for (int s = 0; s < SPL; ++s) lg += part[((size_t)s * BB + b) * NCOL + v];
    lg_row[v] = lg;
    pr_row[v] = 0.0f;
    uint32_t r0, r1;
    tf2x32(ck0, ck1, 0u, (uint32_t)(b * VV + v), r0, r1);
    const uint32_t bits = r0 ^ r1;
    const float u0 = __uint_as_float((bits >> 9) | 0x3f800000u) - 1.0f;
    const float uu = (u0 == 0.0f) ? 1.17549435e-38f : u0;
    const float val = lg - logf(-logf(uu));
    if (val > best) { best = val; besti = v; }   // v ascending -> first max
  }
  // wave reduce (64 lanes)
#pragma unroll
  for (int off = 32; off; off >>= 1) {
    const float vo = __shfl_down(best, off);
    const int   io = __shfl_down(besti, off);
    if (vo > best || (vo == best && io < besti)) { best = vo; besti = io; }
  }
  __shared__ float wv_[16];
  __shared__ int   wi_[16];
  __shared__ int   stok;
  const int wid = tid >> 6, lane = tid & 63;
  if (lane == 0) { wv_[wid] = best; wi_[wid] = besti; }
  __syncthreads();
  if (tid < 64) {
    float v2 = (lane < 16) ? wv_[lane] : -3.4e38f;
    int   i2 = (lane < 16) ? wi_[lane] : 0x7fffffff;
#pragma unroll
    for (int off = 8; off; off >>= 1) {
      const float vo = __shfl_down(v2, off);
      const int   io = __shfl_down(i2, off);
      if (vo > v2 || (vo == v2 && io < i2)) { v2 = vo; i2 = io; }
    }
    if (lane == 0) stok = i2;
  }
  __syncthreads();
  const int tok = stok;
  if (tid == 0) pr_row[tok] = 1.0f;

  if (do_cell) {
    const int u = tid;   // 1024 threads <-> 1024 hidden units
    float zi = bh[u], zf = bh[HH + u], zg = bh[2 * HH + u], zo = bh[3 * HH + u];
#pragma unroll
    for (int s = 0; s < SPL; ++s) {
      const float* p = part + ((size_t)s * BB + b) * NCOL + VV;
      zi += p[u]; zf += p[HH + u]; zg += p[2 * HH + u]; zo += p[3 * HH + u];
    }
    const float* wr = Wi + (size_t)tok * ZC;
    zi += wr[u]; zf += wr[HH + u]; zg += wr[2 * HH + u]; zo += wr[3 * HH + u];
    const float cp = cbuf[b * HH + u];
    const float cc = sigf(zf) * cp + sigf(zi) * tanhf(zg);
    cbuf[b * HH + u] = cc;
    hbuf[b * HH + u] = sigf(zo) * tanhf(cc);
  }
}

}  // namespace

extern "C" void kernel_launch(void* const* d_in, const int* in_sizes, int n_in,
                              void* d_out, int out_size, void* d_ws, size_t ws_size,
                              hipStream_t stream) {
  const float* inputs = (const float*)d_in[0];
  const float* Wi     = (const float*)d_in[1];
  const float* Wh     = (const float*)d_in[2];
  const float* bh     = (const float*)d_in[3];
  const float* Wp     = (const float*)d_in[4];
  const float* bp     = (const float*)d_in[5];
  const float* c0     = (const float*)d_in[6];
  const float* h0     = (const float*)d_in[7];

  float* out_logits = (float*)d_out;
  float* out_preds  = out_logits + (size_t)BB * TT * VV;

  // Workspace layout (part overlaps zpart0: disjoint lifetimes).
  uint8_t* ws = (uint8_t*)d_ws;
  size_t off = 0;
  float* part   = (float*)(ws + off);                 // [SPL][B][NCOL]
  float* zpart0 = (float*)(ws + off);                 // [K0S][B][ZC] (overlap)
  off += (size_t)SPL * BB * NCOL * sizeof(float);     // 6.29 MB
  float* zfull0 = (float*)(ws + off); off += (size_t)BB * ZC * sizeof(float);
  float* cbuf   = (float*)(ws + off); off += (size_t)BB * HH * sizeof(float);
  float* hbuf   = (float*)(ws + off); off += (size_t)BB * HH * sizeof(float);

  // Host-side threefry key chain from jax.random.key(42) = (0, 42).
  uint32_t k0 = 0u, k1 = 42u;
  uint32_t ck[TT][2];
  for (int t = 0; t < TT; ++t) {
    uint32_t a, b2; tf2x32(k0, k1, 0u, 1u, a, b2);
    ck[t][0] = a; ck[t][1] = b2;
    uint32_t n0, n1; tf2x32(k0, k1, 0u, 0u, n0, n1);
    k0 = n0; k1 = n1;
  }

  k0_partial<<<(ZC / 64) * K0S, 256, 0, stream>>>(inputs, h0, Wi, Wh, zpart0);
  k0_reduce<<<BB * ZC / 256, 256, 0, stream>>>(zpart0, bh, zfull0);
  kInit<<<BB * HH / 256, 256, 0, stream>>>(zfull0, c0, cbuf, hbuf);

  for (int t = 0; t < TT; ++t) {
    kA<<<(NCOL / 64) * SPL, 256, 0, stream>>>(hbuf, Wp, Wh, part);
    kB<<<BB, 1024, 0, stream>>>(part, bp, bh, Wi, out_logits, out_preds,
                                cbuf, hbuf, ck[t][0], ck[t][1], t,
                                (t < TT - 1) ? 1 : 0);
  }
}